// Round 17
// baseline (1579.591 us; speedup 1.0000x reference)
//
#include <hip/hip_runtime.h>

#define BB 64
#define SS 2048
#define II 128
#define HH 256
#define OO 128

typedef _Float16 h2_t __attribute__((ext_vector_type(2)));

__device__ __forceinline__ h2_t u2h(unsigned u) {
    union { unsigned u; h2_t h; } c; c.u = u; return c.h;
}

#if __has_builtin(__builtin_amdgcn_fdot2)
__device__ __forceinline__ float fdot2(unsigned h, unsigned w, float acc) {
    return __builtin_amdgcn_fdot2(u2h(h), u2h(w), acc, false);
}
#else
__device__ __forceinline__ float fdot2(unsigned h, unsigned w, float acc) {
    h2_t hh = u2h(h), ww = u2h(w);
    acc = fmaf((float)hh.x, (float)ww.x, acc);
    acc = fmaf((float)hh.y, (float)ww.y, acc);
    return acc;
}
#endif

// ---------------------------------------------------------------------------
// Prep: transpose W_ih -> [I][H], W_fc -> [H][O], combine biases, and write
// the SWIZZLED f16 weight buffer for scan v10:
//   uint4 slot s = w*1024 + (o*4+kk)*64 + l  holds wv[o][kk] for thread
//   (wave w, lane l): sl=l&7, q=l>>3, row j = w*32+sl*4+o,
//   f16s W_hh[j][q*32+kk*8 .. +7]  -> per-step loads are lane-consecutive
//   16B chunks (perfectly coalesced).
// ---------------------------------------------------------------------------
__global__ void prep_kernel(const float* __restrict__ W_ih, const float* __restrict__ b_ih,
                            const float* __restrict__ b_hh, const float* __restrict__ W_fc,
                            float* __restrict__ wihT, float* __restrict__ wfcT,
                            float* __restrict__ biasc, unsigned* __restrict__ wsw,
                            const float* __restrict__ W_hh) {
    int idx = blockIdx.x * 256 + threadIdx.x;      // grid 128*256 = 32768
    if (idx < HH * II) {            // W_ih [H][I] -> wihT [I][H]
        int j = idx / II, k = idx % II;
        wihT[k * HH + j] = W_ih[idx];
    }
    if (idx < OO * HH) {            // W_fc [O][H] -> wfcT [H][O]
        int j = idx / HH, k = idx % HH;
        wfcT[k * OO + j] = W_fc[idx];
    }
    if (idx < HH * (HH / 2)) {      // swizzled scan weights (32768 dwords)
        int d  = idx & 3;
        int s  = idx >> 2;          // uint4 slot
        int l  = s & 63;
        int i  = (s >> 6) & 15;
        int w  = s >> 10;
        int o  = i >> 2;
        int kk = i & 3;
        int sl = l & 7;
        int q  = l >> 3;
        int j  = w * 32 + sl * 4 + o;
        int kb = q * 32 + kk * 8 + d * 2;
        union { h2_t h; unsigned u; } pk;
        pk.h.x = (_Float16)W_hh[j * HH + kb];
        pk.h.y = (_Float16)W_hh[j * HH + kb + 1];
        wsw[idx] = pk.u;
    }
    if (idx < HH) biasc[idx] = b_ih[idx] + b_hh[idx];
}

// ---------------------------------------------------------------------------
// Generic row-major GEMM: C[r][j] = sum_k A[r][k] * Wt[k][j] + bias[j]
// 256 threads, 8x8 micro-tile per thread. (unchanged — scan dominates)
// ---------------------------------------------------------------------------
template<int KD, int JD, int RT>
__global__ __launch_bounds__(256, 2)
void gemm_rk(const float* __restrict__ A, const float* __restrict__ Wt,
             const float* __restrict__ bias, float* __restrict__ C) {
    constexpr int KT = 64;
    constexpr int TJ = JD / 8;
    constexpr int TR = RT / 8;
    static_assert(TJ * TR == 256, "bad tiling");

    __shared__ __align__(16) float a_lds[RT][KT];
    __shared__ __align__(16) float w_lds[KT][JD];

    const int tid = threadIdx.x;
    const int tj = tid % TJ;
    const int tr = tid / TJ;
    const long r0 = (long)blockIdx.x * RT;

    float acc[8][8];
#pragma unroll
    for (int r = 0; r < 8; ++r)
#pragma unroll
        for (int j = 0; j < 8; ++j) acc[r][j] = 0.0f;

    for (int kt = 0; kt < KD; kt += KT) {
        {
            constexpr int NF4 = RT * KT / 4;
#pragma unroll
            for (int f = 0; f < NF4 / 256; ++f) {
                int fl = f * 256 + tid;
                int rr = fl / (KT / 4), kk4 = fl % (KT / 4);
                *(float4*)&a_lds[rr][kk4 * 4] =
                    *(const float4*)&A[(r0 + rr) * KD + kt + kk4 * 4];
            }
        }
        {
            constexpr int NF4 = KT * JD / 4;
#pragma unroll
            for (int f = 0; f < NF4 / 256; ++f) {
                int fl = f * 256 + tid;
                int kk = fl / (JD / 4), jj4 = fl % (JD / 4);
                *(float4*)&w_lds[kk][jj4 * 4] =
                    *(const float4*)&Wt[(long)(kt + kk) * JD + jj4 * 4];
            }
        }
        __syncthreads();

#pragma unroll 4
        for (int k4 = 0; k4 < KT; k4 += 4) {
            float4 xv[8];
#pragma unroll
            for (int r = 0; r < 8; ++r)
                xv[r] = *(const float4*)&a_lds[tr * 8 + r][k4];
#pragma unroll
            for (int i = 0; i < 4; ++i) {
                float4 wa = *(const float4*)&w_lds[k4 + i][tj * 8];
                float4 wb = *(const float4*)&w_lds[k4 + i][tj * 8 + 4];
#pragma unroll
                for (int r = 0; r < 8; ++r) {
                    float xs = (i == 0) ? xv[r].x : (i == 1) ? xv[r].y
                             : (i == 2) ? xv[r].z : xv[r].w;
                    acc[r][0] = fmaf(xs, wa.x, acc[r][0]);
                    acc[r][1] = fmaf(xs, wa.y, acc[r][1]);
                    acc[r][2] = fmaf(xs, wa.z, acc[r][2]);
                    acc[r][3] = fmaf(xs, wa.w, acc[r][3]);
                    acc[r][4] = fmaf(xs, wb.x, acc[r][4]);
                    acc[r][5] = fmaf(xs, wb.y, acc[r][5]);
                    acc[r][6] = fmaf(xs, wb.z, acc[r][6]);
                    acc[r][7] = fmaf(xs, wb.w, acc[r][7]);
                }
            }
        }
        __syncthreads();
    }

    float4 b0 = *(const float4*)&bias[tj * 8];
    float4 b1 = *(const float4*)&bias[tj * 8 + 4];
#pragma unroll
    for (int r = 0; r < 8; ++r) {
        long row = r0 + tr * 8 + r;
        float4 o0, o1;
        o0.x = acc[r][0] + b0.x; o0.y = acc[r][1] + b0.y;
        o0.z = acc[r][2] + b0.z; o0.w = acc[r][3] + b0.w;
        o1.x = acc[r][4] + b1.x; o1.y = acc[r][5] + b1.y;
        o1.z = acc[r][6] + b1.z; o1.w = acc[r][7] + b1.w;
        *(float4*)&C[row * JD + tj * 8]     = o0;
        *(float4*)&C[row * JD + tj * 8 + 4] = o1;
    }
}

// ---------------------------------------------------------------------------
// Sequential scan v10: h_t = tanh(xp_t + h_{t-1} @ W_hh^T), in-place.
// 64 blocks x 512 threads (8 waves). Weights stream from L2 (v9's win).
//
// v9 lesson (m134 arithmetic): broadcast LDS reads charge PER-LANE bytes:
// 512thr x 128B = 64KB/CU/step = ~950 LDS-pipe cyc — the floor since v1.
// v10: thread = 4 outputs x 32 k's -> 64B/lane (32 b128/CU, ~384 cyc), and
// a 2-phase reduction: stage A shfl_xor(8) per output (4 shfls), then the
// rotated-slot trick over the 4 remaining groups (3 shfls + cndmask picks;
// lane ends owning ONE output g=q>>1) -> 7 shfls vs naive 12, tanh /4.
// h in LDS: 8 groups x 40 f16 (80B stride: 16B-aligned, banks q*20%32
// distinct). Writers: lanes with even q (one per output).
// ---------------------------------------------------------------------------
__global__ __attribute__((amdgpu_waves_per_eu(2, 2))) __launch_bounds__(512)
void rnn_scan(const unsigned* __restrict__ wsw, float* __restrict__ hid) {
    const int b   = blockIdx.x;
    const int tid = threadIdx.x;
    const int w   = tid >> 6;
    const int l   = tid & 63;
    const int sl  = l & 7;         // output-quad selector
    const int q   = l >> 3;        // k-group 0..7
    const int g   = q >> 1;        // owned output slot 0..3

    const int jown = w * 32 + sl * 4 + g;    // this thread's owned output

    __shared__ __align__(16) _Float16 h16[2][8 * 40];

    // per-thread weight stream base (lane-consecutive 16B chunks);
    // 4 sub-bases keep all imm offsets <= 3072B
    const uint4* __restrict__ wp0 = (const uint4*)wsw + ((size_t)w << 10) + l;
    const uint4* __restrict__ wp1 = wp0 + 256;
    const uint4* __restrict__ wp2 = wp0 + 512;
    const uint4* __restrict__ wp3 = wp0 + 768;

    for (int i = tid; i < 2 * 320 / 2; i += 512) ((unsigned*)h16)[i] = 0u;

    float* __restrict__ base = hid + (size_t)b * SS * HH;
    float xp0 = base[jown];
    float xp1 = base[HH + jown];
    __syncthreads();

#pragma unroll 1
    for (int t = 0; t < SS; ++t) {
        // stream this step's weights from L2 (coalesced 1KB/instr)
        uint4 w0[4], w1[4], w2[4], w3[4];
#pragma unroll
        for (int kk = 0; kk < 4; ++kk) {
            w0[kk] = wp0[kk * 64];
            w1[kk] = wp1[kk * 64];
            w2[kk] = wp2[kk * 64];
            w3[kk] = wp3[kk * 64];
        }

        // branchless clamped xp prefetch for t+2
        const int t2 = (t + 2 < SS) ? (t + 2) : (SS - 1);
        float xp2 = base[(size_t)t2 * HH + jown];

        const uint4* hb = (const uint4*)&h16[t & 1][q * 40];
        float p0 = 0.f, p1 = 0.f, p2 = 0.f, p3 = 0.f;
#pragma unroll
        for (int kk = 0; kk < 4; ++kk) {
            uint4 hv = hb[kk];
            p0 = fdot2(hv.x, w0[kk].x, p0);
            p0 = fdot2(hv.y, w0[kk].y, p0);
            p0 = fdot2(hv.z, w0[kk].z, p0);
            p0 = fdot2(hv.w, w0[kk].w, p0);
            p1 = fdot2(hv.x, w1[kk].x, p1);
            p1 = fdot2(hv.y, w1[kk].y, p1);
            p1 = fdot2(hv.z, w1[kk].z, p1);
            p1 = fdot2(hv.w, w1[kk].w, p1);
            p2 = fdot2(hv.x, w2[kk].x, p2);
            p2 = fdot2(hv.y, w2[kk].y, p2);
            p2 = fdot2(hv.z, w2[kk].z, p2);
            p2 = fdot2(hv.w, w2[kk].w, p2);
            p3 = fdot2(hv.x, w3[kk].x, p3);
            p3 = fdot2(hv.y, w3[kk].y, p3);
            p3 = fdot2(hv.z, w3[kk].z, p3);
            p3 = fdot2(hv.w, w3[kk].w, p3);
        }

        // stage A: combine q with q^1 (lane^8) for all 4 outputs
        p0 += __shfl_xor(p0, 8, 64);
        p1 += __shfl_xor(p1, 8, 64);
        p2 += __shfl_xor(p2, 8, 64);
        p3 += __shfl_xor(p3, 8, 64);

        // rotated-slot reduction over the 4 remaining groups (lane bits 4,5):
        // lane owns slot g; round r: receive partner(l^(r<<4))'s partial[g]
        float s  = (g == 0) ? p0 : (g == 1) ? p1 : (g == 2) ? p2 : p3;
        float x1 = (g == 0) ? p1 : (g == 1) ? p0 : (g == 2) ? p3 : p2;  // partial[g^1]
        s += __shfl_xor(x1, 16, 64);
        float x2 = (g == 0) ? p2 : (g == 1) ? p3 : (g == 2) ? p0 : p1;  // partial[g^2]
        s += __shfl_xor(x2, 32, 64);
        float x3 = (g == 0) ? p3 : (g == 1) ? p2 : (g == 2) ? p1 : p0;  // partial[g^3]
        s += __shfl_xor(x3, 48, 64);

        s += xp0;
        // tanh(s) = 1 - 2/(e^{2s}+1); overflow-safe without clamps
        float e  = __expf(2.0f * s);
        float hn = 1.0f - __fdividef(2.0f, e + 1.0f);

        if (!(q & 1)) {           // one writer per output
            h16[(t & 1) ^ 1][(jown >> 5) * 40 + (jown & 31)] = (_Float16)hn;
            base[(size_t)t * HH + jown] = hn;
        }
        __syncthreads();
        xp0 = xp1;
        xp1 = xp2;
    }
}

// ---------------------------------------------------------------------------
extern "C" void kernel_launch(void* const* d_in, const int* in_sizes, int n_in,
                              void* d_out, int out_size, void* d_ws, size_t ws_size,
                              hipStream_t stream) {
    const float* x    = (const float*)d_in[0];
    const float* W_ih = (const float*)d_in[1];
    const float* W_hh = (const float*)d_in[2];
    const float* b_ih = (const float*)d_in[3];
    const float* b_hh = (const float*)d_in[4];
    const float* W_fc = (const float*)d_in[5];
    const float* b_fc = (const float*)d_in[6];

    float* out_fc  = (float*)d_out;                          // [B][S][O]
    float* hidden  = (float*)d_out + (size_t)BB * SS * OO;   // [B][S][H]

    float*    wihT  = (float*)d_ws;                  // [I][H]  32768 f
    float*    wfcT  = wihT + II * HH;                // [H][O]  32768 f
    float*    biasc = wfcT + HH * OO;                // [H]       256 f
    unsigned* wsw   = (unsigned*)(biasc + HH);       // swizzled [32768] u32

    const long NR = (long)BB * SS;                   // 131072 rows

    prep_kernel<<<128, 256, 0, stream>>>(W_ih, b_ih, b_hh, W_fc,
                                         wihT, wfcT, biasc, wsw, W_hh);
    gemm_rk<II, HH, 64><<<NR / 64, 256, 0, stream>>>(x, wihT, biasc, hidden);
    rnn_scan<<<BB, 512, 0, stream>>>(wsw, hidden);
    gemm_rk<HH, OO, 128><<<NR / 128, 256, 0, stream>>>(hidden, wfcT, b_fc, out_fc);
}